// Round 1
// baseline (368.737 us; speedup 1.0000x reference)
//
#include <hip/hip_runtime.h>
#include <math.h>

// Problem constants (validated against in_sizes at runtime where cheap)
// N = 20000, E = 640000, IN_DIM = HID = 128, OUT = 64

// ---------------- CSR build ----------------

__global__ void count_kernel(const int* __restrict__ eidx, int E, int* __restrict__ cnt) {
    int e = blockIdx.x * blockDim.x + threadIdx.x;
    if (e < E) atomicAdd(&cnt[eidx[E + e]], 1);
}

__global__ __launch_bounds__(1024) void scan_kernel(
    const int* __restrict__ cnt, int N, int E,
    int* __restrict__ row_ptr, int* __restrict__ wptr,
    float* __restrict__ dinv, float* __restrict__ rcnt)
{
    __shared__ int sdata[1024];
    __shared__ int carry;
    int tid = threadIdx.x;
    if (tid == 0) carry = 0;
    __syncthreads();
    for (int base = 0; base < N; base += 1024) {
        int i = base + tid;
        int v = (i < N) ? cnt[i] : 0;
        sdata[tid] = v;
        __syncthreads();
        // inclusive Hillis-Steele scan
        for (int off = 1; off < 1024; off <<= 1) {
            int t = (tid >= off) ? sdata[tid - off] : 0;
            __syncthreads();
            sdata[tid] += t;
            __syncthreads();
        }
        int c = carry;
        int excl = c + sdata[tid] - v;
        if (i < N) {
            row_ptr[i] = excl;
            wptr[i]    = excl;
            dinv[i]    = 1.0f / sqrtf((float)(v + 1));   // GCN deg includes self loop
            rcnt[i]    = 1.0f / (float)((v > 0) ? v : 1); // SAGE mean denominator
        }
        __syncthreads();
        if (tid == 1023) carry = c + sdata[1023];
        __syncthreads();
    }
    if (tid == 0) row_ptr[N] = E;
}

__global__ void fill_kernel(const int* __restrict__ eidx, int E,
                            int* __restrict__ wptr, int* __restrict__ col) {
    int e = blockIdx.x * blockDim.x + threadIdx.x;
    if (e < E) {
        int d = eidx[E + e];
        int s = eidx[e];
        int p = atomicAdd(&wptr[d], 1);
        col[p] = s;
    }
}

// ---------------- sparse aggregation (wave per node) ----------------
// GCN: Y[d] = relu(dinv[d] * (sum_{e in row d} X[col[e]] + X[d]) + bias)
// SAGE-mean pre: Y[d] = rcnt[d] * sum_{e in row d} X[col[e]]

template<bool GCN>
__global__ __launch_bounds__(256) void agg_kernel(
    const float* __restrict__ X, const int* __restrict__ row_ptr,
    const int* __restrict__ col, const float* __restrict__ dinv,
    const float* __restrict__ rcnt, const float* __restrict__ bias,
    float* __restrict__ Y, int N)
{
    int w = (int)((blockIdx.x * blockDim.x + threadIdx.x) >> 6);
    int lane = threadIdx.x & 63;
    if (w >= N) return;
    const float2* X2 = (const float2*)X;
    float2 acc;
    if (GCN) acc = X2[(size_t)w * 64 + lane];  // self loop contribution
    else { acc.x = 0.f; acc.y = 0.f; }
    int beg = row_ptr[w], end = row_ptr[w + 1];
    for (int base = beg; base < end; base += 64) {
        int rem = end - base;
        int n = rem < 64 ? rem : 64;
        int idx = 0;
        if (lane < n) idx = col[base + lane];
        int j = 0;
        for (; j + 4 <= n; j += 4) {
            int s0 = __shfl(idx, j);
            int s1 = __shfl(idx, j + 1);
            int s2 = __shfl(idx, j + 2);
            int s3 = __shfl(idx, j + 3);
            float2 v0 = X2[(size_t)s0 * 64 + lane];
            float2 v1 = X2[(size_t)s1 * 64 + lane];
            float2 v2 = X2[(size_t)s2 * 64 + lane];
            float2 v3 = X2[(size_t)s3 * 64 + lane];
            acc.x += v0.x + v1.x + v2.x + v3.x;
            acc.y += v0.y + v1.y + v2.y + v3.y;
        }
        for (; j < n; j++) {
            int s = __shfl(idx, j);
            float2 v = X2[(size_t)s * 64 + lane];
            acc.x += v.x; acc.y += v.y;
        }
    }
    float2 out;
    if (GCN) {
        float dv = dinv[w];
        const float2* b2 = (const float2*)bias;
        float2 b = b2[lane];
        out.x = fmaxf(fmaf(acc.x, dv, b.x), 0.f);
        out.y = fmaxf(fmaf(acc.y, dv, b.y), 0.f);
    } else {
        float rc = rcnt[w];
        out.x = acc.x * rc;
        out.y = acc.y * rc;
    }
    ((float2*)Y)[(size_t)w * 64 + lane] = out;
}

// ---------------- dense GEMM (fp32, K=128 fixed, A stride 128) ----------------
// C[nrows, NCOL] = act(A[nrows,128] @ W[128,NCOL] ...)

enum { ACT_BIAS = 0, ACT_SCALE = 1, ACT_RELU_ACC = 2, ACT_GELU = 3 };

__device__ __forceinline__ float gelu_exact(float x) {
    return 0.5f * x * (1.0f + erff(x * 0.70710678118654752440f));
}

template<int NCOL, int ACT>
__global__ __launch_bounds__(256) void gemm_kernel(
    const float* __restrict__ A, const float* __restrict__ W,
    const float* __restrict__ bias, const float* __restrict__ rowscale,
    const float* __restrict__ Cin, float* __restrict__ C, int nrows)
{
    constexpr int CG = NCOL / 4;   // col groups of 4
    constexpr int RG = 256 / CG;   // row groups of 4
    constexpr int BM = RG * 4;     // rows per block (32 or 64)
    constexpr int TK = 64;         // K staged per W-tile
    __shared__ __align__(16) float Ws[TK][NCOL];
    __shared__ __align__(16) float At[128][BM + 4];  // transposed A tile, padded

    int tid = threadIdx.x;
    int row0 = blockIdx.x * BM;

    // stage A tile transposed: At[k][r] = A[row0+r][k]
    for (int it = tid; it < BM * 32; it += 256) {
        int r = it >> 5;
        int k4 = (it & 31) << 2;
        int row = row0 + r;
        float4 v = make_float4(0.f, 0.f, 0.f, 0.f);
        if (row < nrows) v = *(const float4*)(A + (size_t)row * 128 + k4);
        At[k4 + 0][r] = v.x; At[k4 + 1][r] = v.y;
        At[k4 + 2][r] = v.z; At[k4 + 3][r] = v.w;
    }

    int cg = tid % CG, rg = tid / CG;
    float acc[4][4] = {};

    for (int kt = 0; kt < 128; kt += TK) {
        __syncthreads();
        // stage W rows [kt, kt+TK)
        for (int it = tid; it < TK * CG; it += 256) {
            int k = it / CG;
            int c4 = (it % CG) * 4;
            *(float4*)&Ws[k][c4] = *(const float4*)(W + (size_t)(kt + k) * NCOL + c4);
        }
        __syncthreads();
        #pragma unroll 8
        for (int k = 0; k < TK; k++) {
            float4 a = *(const float4*)&At[kt + k][rg * 4];
            float4 w = *(const float4*)&Ws[k][cg * 4];
            float ar[4] = {a.x, a.y, a.z, a.w};
            float wc[4] = {w.x, w.y, w.z, w.w};
            #pragma unroll
            for (int r = 0; r < 4; r++)
                #pragma unroll
                for (int c = 0; c < 4; c++)
                    acc[r][c] = fmaf(ar[r], wc[c], acc[r][c]);
        }
    }

    // epilogue
    float4 b = make_float4(0.f, 0.f, 0.f, 0.f);
    if (ACT == ACT_BIAS || ACT == ACT_GELU)
        b = *(const float4*)(bias + cg * 4);
    #pragma unroll
    for (int r = 0; r < 4; r++) {
        int row = row0 + rg * 4 + r;
        if (row >= nrows) break;
        float o0 = acc[r][0], o1 = acc[r][1], o2 = acc[r][2], o3 = acc[r][3];
        if (ACT == ACT_BIAS || ACT == ACT_GELU) {
            o0 += b.x; o1 += b.y; o2 += b.z; o3 += b.w;
        }
        if (ACT == ACT_SCALE) {
            float s = rowscale[row];
            o0 *= s; o1 *= s; o2 *= s; o3 *= s;
        }
        if (ACT == ACT_RELU_ACC) {
            float4 ci = *(const float4*)(Cin + (size_t)row * NCOL + cg * 4);
            o0 = fmaxf(o0 + ci.x, 0.f); o1 = fmaxf(o1 + ci.y, 0.f);
            o2 = fmaxf(o2 + ci.z, 0.f); o3 = fmaxf(o3 + ci.w, 0.f);
        }
        if (ACT == ACT_GELU) {
            o0 = gelu_exact(o0); o1 = gelu_exact(o1);
            o2 = gelu_exact(o2); o3 = gelu_exact(o3);
        }
        float4 o = make_float4(o0, o1, o2, o3);
        *(float4*)(C + (size_t)row * NCOL + cg * 4) = o;
    }
}

// ---------------- value head: out[i] = dot(h2[i,:], Wv) + bv ----------------

__global__ __launch_bounds__(256) void value_kernel(
    const float* __restrict__ h2, const float* __restrict__ Wv,
    const float* __restrict__ bv, float* __restrict__ out, int N)
{
    int w = (int)((blockIdx.x * blockDim.x + threadIdx.x) >> 6);
    int lane = threadIdx.x & 63;
    if (w >= N) return;
    float2 h = ((const float2*)h2)[(size_t)w * 64 + lane];
    float2 wv = ((const float2*)Wv)[lane];
    float p = fmaf(h.x, wv.x, h.y * wv.y);
    for (int off = 32; off; off >>= 1) p += __shfl_down(p, off);
    if (lane == 0) out[w] = p + bv[0];
}

// ---------------- launch ----------------

extern "C" void kernel_launch(void* const* d_in, const int* in_sizes, int n_in,
                              void* d_out, int out_size, void* d_ws, size_t ws_size,
                              hipStream_t stream) {
    const float* feat  = (const float*)d_in[0];
    const int*   eidx  = (const int*)d_in[1];
    const float* W_gcn = (const float*)d_in[2];
    const float* b_gcn = (const float*)d_in[3];
    const float* W_sl  = (const float*)d_in[4];
    const float* b_sl  = (const float*)d_in[5];
    const float* W_sr  = (const float*)d_in[6];
    const float* W1    = (const float*)d_in[7];
    const float* b1    = (const float*)d_in[8];
    const float* W2    = (const float*)d_in[9];
    const float* b2    = (const float*)d_in[10];
    const float* W3    = (const float*)d_in[11];
    const float* b3    = (const float*)d_in[12];
    const float* Wv    = (const float*)d_in[13];
    const float* bv    = (const float*)d_in[14];

    const int N = in_sizes[0] / 128;
    const int E = in_sizes[1] / 2;

    char* ws = (char*)d_ws;
    size_t off = 0;
    auto alloc = [&](size_t bytes) -> void* {
        void* p = ws + off;
        off += (bytes + 255) & ~(size_t)255;
        return p;
    };
    int*   cnt     = (int*)alloc((size_t)N * 4);
    int*   row_ptr = (int*)alloc((size_t)(N + 1) * 4);
    int*   wptr    = (int*)alloc((size_t)N * 4);
    float* dinv    = (float*)alloc((size_t)N * 4);
    float* rcnt    = (float*)alloc((size_t)N * 4);
    int*   col     = (int*)alloc((size_t)E * 4);
    float* xs      = (float*)alloc((size_t)N * 128 * 4);
    float* h1      = (float*)alloc((size_t)N * 128 * 4);
    float* h2      = (float*)alloc((size_t)N * 128 * 4);
    float* bufA    = (float*)alloc((size_t)N * 128 * 4);
    float* bufB    = (float*)alloc((size_t)N * 128 * 4);

    // CSR build
    hipMemsetAsync(cnt, 0, (size_t)N * 4, stream);
    count_kernel<<<(E + 255) / 256, 256, 0, stream>>>(eidx, E, cnt);
    scan_kernel<<<1, 1024, 0, stream>>>(cnt, N, E, row_ptr, wptr, dinv, rcnt);
    fill_kernel<<<(E + 255) / 256, 256, 0, stream>>>(eidx, E, wptr, col);

    const int gb128 = (N + 31) / 32;
    const int gb64  = (N + 63) / 64;
    const int agrid = (N + 3) / 4;   // wave per node, 4 waves/block

    // GCN: xs = (feat @ W_gcn) * dinv[:,None]
    gemm_kernel<128, ACT_SCALE><<<gb128, 256, 0, stream>>>(feat, W_gcn, nullptr, dinv, nullptr, xs, N);
    // h1 = relu(dinv * (sum xs[src] + xs[self]) + b_gcn)
    agg_kernel<true><<<agrid, 256, 0, stream>>>(xs, row_ptr, col, dinv, rcnt, b_gcn, h1, N);
    // SAGE mean aggregation -> bufA
    agg_kernel<false><<<agrid, 256, 0, stream>>>(h1, row_ptr, col, dinv, rcnt, nullptr, bufA, N);
    // bufB = mean @ W_sl + b_sl
    gemm_kernel<128, ACT_BIAS><<<gb128, 256, 0, stream>>>(bufA, W_sl, b_sl, nullptr, nullptr, bufB, N);
    // h2 = relu(bufB + h1 @ W_sr)
    gemm_kernel<128, ACT_RELU_ACC><<<gb128, 256, 0, stream>>>(h1, W_sr, nullptr, nullptr, bufB, h2, N);
    // policy MLP
    gemm_kernel<128, ACT_GELU><<<gb128, 256, 0, stream>>>(h2, W1, b1, nullptr, nullptr, bufA, N);
    gemm_kernel<128, ACT_GELU><<<gb128, 256, 0, stream>>>(bufA, W2, b2, nullptr, nullptr, bufB, N);
    // means -> d_out[0 : N*64)
    gemm_kernel<64, ACT_BIAS><<<gb64, 256, 0, stream>>>(bufB, W3, b3, nullptr, nullptr, (float*)d_out, N);
    // values -> d_out[N*64 : N*64+N)
    value_kernel<<<agrid, 256, 0, stream>>>(h2, Wv, bv, (float*)d_out + (size_t)N * 64, N);
}

// Round 2
// 205.073 us; speedup vs baseline: 1.7981x; 1.7981x over previous
//
#include <hip/hip_runtime.h>
#include <math.h>

// N = 20000, E = 640000, IN_DIM = HID = 128, OUT = 64
// Activations kept as bf16 (ushort bits), accumulation fp32 via MFMA 16x16x32.

typedef __attribute__((ext_vector_type(8))) short short8;
typedef __attribute__((ext_vector_type(4))) float floatx4;

__device__ __forceinline__ unsigned short f2b(float f) {
    unsigned u = __float_as_uint(f);
    unsigned r = (u + 0x7fffu + ((u >> 16) & 1u)) >> 16;
    return (unsigned short)r;
}
__device__ __forceinline__ float b2f(unsigned short h) {
    return __uint_as_float(((unsigned)h) << 16);
}
__device__ __forceinline__ float b2f_lo(unsigned v) {
    return __uint_as_float(v << 16);
}
__device__ __forceinline__ float b2f_hi(unsigned v) {
    return __uint_as_float(v & 0xffff0000u);
}
__device__ __forceinline__ floatx4 MFMA(short8 a, short8 b, floatx4 c) {
    return __builtin_amdgcn_mfma_f32_16x16x32_bf16(a, b, c, 0, 0, 0);
}
__device__ __forceinline__ float gelu_exact(float x) {
    return 0.5f * x * (1.0f + erff(x * 0.70710678118654752440f));
}

// B fragment for (ct, ks) at lane: packed W layout
#define FRAG(P, ct, ks, lane) (*(const short8*)((P) + (((((ct)*4 + (ks))*64) + (lane)) << 3)))

// ---------------- count (+rank) fused with weight packing ----------------
// Pack: Wp[((ct*4+ks)*64 + l)*8 + j] = bf16(W[(ks*32 + (l>>4)*8 + j)*NC + ct*16 + (l&15)])

__global__ __launch_bounds__(256) void count_pack_kernel(
    const int* __restrict__ eidx, int E,
    int* __restrict__ cnt, int* __restrict__ rank,
    const float* Wg, const float* Wsl, const float* Wsr,
    const float* W1, const float* W2, const float* W3,
    unsigned short* Pg, unsigned short* Psl, unsigned short* Psr,
    unsigned short* P1, unsigned short* P2, unsigned short* P3,
    int countBlocks)
{
    if ((int)blockIdx.x < countBlocks) {
        int e = blockIdx.x * 256 + threadIdx.x;
        if (e < E) {
            int d = eidx[E + e];
            rank[e] = atomicAdd(&cnt[d], 1);
        }
        return;
    }
    int t = (blockIdx.x - countBlocks) * 256 + threadIdx.x;
    const float* W; unsigned short* P; int NC = 128; int base;
    if (t < 2048)       { W = Wg;  P = Pg;  base = t; }
    else if (t < 4096)  { W = Wsl; P = Psl; base = t - 2048; }
    else if (t < 6144)  { W = Wsr; P = Psr; base = t - 4096; }
    else if (t < 8192)  { W = W1;  P = P1;  base = t - 6144; }
    else if (t < 10240) { W = W2;  P = P2;  base = t - 8192; }
    else if (t < 11264) { W = W3;  P = P3;  base = t - 10240; NC = 64; }
    else return;
    int l  = base & 63;
    int ks = (base >> 6) & 3;
    int ct = base >> 8;
    int n  = ct * 16 + (l & 15);
    int k0 = ks * 32 + ((l >> 4) << 3);
    short8 v;
    #pragma unroll
    for (int j = 0; j < 8; j++) v[j] = (short)f2b(W[(size_t)(k0 + j) * NC + n]);
    *(short8*)(P + ((size_t)base << 3)) = v;
}

// ---------------- scan phase A (local) fused with GCN GEMM ----------------
// GCN GEMM: xs = bf16(feat @ W_gcn)  (raw, dinv applied in agg)

__global__ __launch_bounds__(256) void scanA_gemm_kernel(
    const int* __restrict__ cnt, int N,
    int* __restrict__ row_ptr, int* __restrict__ blocksums, int scanBlocks,
    const float* __restrict__ feat, const unsigned short* __restrict__ Pg,
    unsigned short* __restrict__ xs, int M)
{
    if ((int)blockIdx.x < scanBlocks) {
        __shared__ int sh[256];
        int b = blockIdx.x, tid = threadIdx.x;
        int i0 = b * 1024 + tid * 4;
        int v0 = (i0 + 0 < N) ? cnt[i0 + 0] : 0;
        int v1 = (i0 + 1 < N) ? cnt[i0 + 1] : 0;
        int v2 = (i0 + 2 < N) ? cnt[i0 + 2] : 0;
        int v3 = (i0 + 3 < N) ? cnt[i0 + 3] : 0;
        int tot = v0 + v1 + v2 + v3;
        sh[tid] = tot;
        __syncthreads();
        for (int off = 1; off < 256; off <<= 1) {
            int t = (tid >= off) ? sh[tid - off] : 0;
            __syncthreads();
            sh[tid] += t;
            __syncthreads();
        }
        int excl = sh[tid] - tot;
        if (i0 + 0 < N) row_ptr[i0 + 0] = excl;
        if (i0 + 1 < N) row_ptr[i0 + 1] = excl + v0;
        if (i0 + 2 < N) row_ptr[i0 + 2] = excl + v0 + v1;
        if (i0 + 3 < N) row_ptr[i0 + 3] = excl + v0 + v1 + v2;
        if (tid == 255) blocksums[b] = sh[255];
        return;
    }
    // GCN GEMM: wave computes 16 rows x 64 cols
    int bid = blockIdx.x - scanBlocks;
    int w = bid * 4 + (threadIdx.x >> 6);
    if (w >= (M / 16) * 2) return;
    int lane = threadIdx.x & 63;
    int m = lane & 15, quad = lane >> 4;
    int rt = w >> 1, ch = w & 1;
    const float* arow = feat + (size_t)(rt * 16 + m) * 128;
    short8 a[4];
    #pragma unroll
    for (int ks = 0; ks < 4; ks++) {
        float4 f0 = *(const float4*)(arow + ks * 32 + quad * 8);
        float4 f1 = *(const float4*)(arow + ks * 32 + quad * 8 + 4);
        short8 s;
        s[0] = (short)f2b(f0.x); s[1] = (short)f2b(f0.y);
        s[2] = (short)f2b(f0.z); s[3] = (short)f2b(f0.w);
        s[4] = (short)f2b(f1.x); s[5] = (short)f2b(f1.y);
        s[6] = (short)f2b(f1.z); s[7] = (short)f2b(f1.w);
        a[ks] = s;
    }
    #pragma unroll
    for (int ct = 0; ct < 4; ct++) {
        floatx4 acc = {0.f, 0.f, 0.f, 0.f};
        #pragma unroll
        for (int ks = 0; ks < 4; ks++)
            acc = MFMA(a[ks], FRAG(Pg, ch * 4 + ct, ks, lane), acc);
        #pragma unroll
        for (int reg = 0; reg < 4; reg++)
            xs[(size_t)(rt * 16 + quad * 4 + reg) * 128 + (ch * 4 + ct) * 16 + m] =
                f2b(acc[reg]);
    }
}

// ---------------- scan phase C: add cross-block offsets, derive dinv/rcnt ----

__global__ __launch_bounds__(256) void scanC_kernel(
    const int* __restrict__ cnt, const int* __restrict__ blocksums,
    int N, int E, int* __restrict__ row_ptr,
    float* __restrict__ dinv, float* __restrict__ rcnt)
{
    int b = blockIdx.x, tid = threadIdx.x;
    int offset = 0;
    for (int j = 0; j < b; j++) offset += blocksums[j];
    int i0 = b * 1024 + tid * 4;
    #pragma unroll
    for (int q = 0; q < 4; q++) {
        int i = i0 + q;
        if (i < N) {
            row_ptr[i] += offset;
            int c = cnt[i];
            dinv[i] = rsqrtf((float)(c + 1));
            rcnt[i] = 1.0f / (float)(c > 0 ? c : 1);
        }
    }
    if (b == 0 && tid == 0) row_ptr[N] = E;
}

// ---------------- fill (atomic-free scatter via rank) ----------------

__global__ void fill_kernel(const int* __restrict__ eidx, const int* __restrict__ rank,
                            const int* __restrict__ row_ptr, int E, int* __restrict__ col)
{
    int e = blockIdx.x * blockDim.x + threadIdx.x;
    if (e < E) {
        int d = eidx[E + e];
        col[row_ptr[d] + rank[e]] = eidx[e];
    }
}

// ---------------- aggregation (bf16, wave per node) ----------------
// GCN:  h1[d] = relu(dinv[d]*(sum_s dinv[s]*xs[s] + dinv[d]*xs[d]) + b)
// SAGE: mean[d] = rcnt[d] * sum_s h1[s]

template<bool GCN>
__global__ __launch_bounds__(256) void agg_kernel(
    const unsigned short* __restrict__ X, const int* __restrict__ row_ptr,
    const int* __restrict__ col, const float* __restrict__ dinv,
    const float* __restrict__ rcnt, const float* __restrict__ bias,
    unsigned short* __restrict__ Y, int N)
{
    int w = (int)((blockIdx.x * 256 + threadIdx.x) >> 6);
    int lane = threadIdx.x & 63;
    if (w >= N) return;
    const unsigned* Xu = (const unsigned*)X;
    float ax = 0.f, ay = 0.f;
    if (GCN) {
        unsigned v = Xu[(size_t)w * 64 + lane];
        float dv = dinv[w];
        ax = b2f_lo(v) * dv;
        ay = b2f_hi(v) * dv;
    }
    int beg = row_ptr[w], end = row_ptr[w + 1];
    for (int base = beg; base < end; base += 64) {
        int rem = end - base;
        int n = rem < 64 ? rem : 64;
        int idx = (lane < n) ? col[base + lane] : 0;
        int j = 0;
        for (; j + 4 <= n; j += 4) {
            int s0 = __shfl(idx, j);
            int s1 = __shfl(idx, j + 1);
            int s2 = __shfl(idx, j + 2);
            int s3 = __shfl(idx, j + 3);
            unsigned v0 = Xu[(size_t)s0 * 64 + lane];
            unsigned v1 = Xu[(size_t)s1 * 64 + lane];
            unsigned v2 = Xu[(size_t)s2 * 64 + lane];
            unsigned v3 = Xu[(size_t)s3 * 64 + lane];
            if (GCN) {
                float d0 = dinv[s0], d1 = dinv[s1], d2 = dinv[s2], d3 = dinv[s3];
                ax = fmaf(b2f_lo(v0), d0, ax); ay = fmaf(b2f_hi(v0), d0, ay);
                ax = fmaf(b2f_lo(v1), d1, ax); ay = fmaf(b2f_hi(v1), d1, ay);
                ax = fmaf(b2f_lo(v2), d2, ax); ay = fmaf(b2f_hi(v2), d2, ay);
                ax = fmaf(b2f_lo(v3), d3, ax); ay = fmaf(b2f_hi(v3), d3, ay);
            } else {
                ax += b2f_lo(v0) + b2f_lo(v1) + b2f_lo(v2) + b2f_lo(v3);
                ay += b2f_hi(v0) + b2f_hi(v1) + b2f_hi(v2) + b2f_hi(v3);
            }
        }
        for (; j < n; j++) {
            int s = __shfl(idx, j);
            unsigned v = Xu[(size_t)s * 64 + lane];
            if (GCN) {
                float d = dinv[s];
                ax = fmaf(b2f_lo(v), d, ax); ay = fmaf(b2f_hi(v), d, ay);
            } else {
                ax += b2f_lo(v); ay += b2f_hi(v);
            }
        }
    }
    float ox, oy;
    if (GCN) {
        float dv = dinv[w];
        float2 b = ((const float2*)bias)[lane];
        ox = fmaxf(fmaf(ax, dv, b.x), 0.f);
        oy = fmaxf(fmaf(ay, dv, b.y), 0.f);
    } else {
        float rc = rcnt[w];
        ox = ax * rc;
        oy = ay * rc;
    }
    unsigned out = (unsigned)f2b(ox) | ((unsigned)f2b(oy) << 16);
    ((unsigned*)Y)[(size_t)w * 64 + lane] = out;
}

// ---------------- fused SAGE GEMM: h2 = relu(mean@Wsl + h1@Wsr + bsl) -------

__global__ __launch_bounds__(256) void sage_gemm_kernel(
    const unsigned short* __restrict__ mean, const unsigned short* __restrict__ h1,
    const unsigned short* __restrict__ Psl, const unsigned short* __restrict__ Psr,
    const float* __restrict__ bsl, unsigned short* __restrict__ h2, int M)
{
    int w = blockIdx.x * 4 + (threadIdx.x >> 6);
    if (w >= (M / 16) * 2) return;
    int lane = threadIdx.x & 63;
    int m = lane & 15, quad = lane >> 4;
    int rt = w >> 1, ch = w & 1;
    short8 am[4], ar[4];
    #pragma unroll
    for (int ks = 0; ks < 4; ks++) {
        am[ks] = *(const short8*)(mean + (size_t)(rt * 16 + m) * 128 + ks * 32 + quad * 8);
        ar[ks] = *(const short8*)(h1   + (size_t)(rt * 16 + m) * 128 + ks * 32 + quad * 8);
    }
    #pragma unroll
    for (int ct = 0; ct < 4; ct++) {
        floatx4 acc = {0.f, 0.f, 0.f, 0.f};
        int gct = ch * 4 + ct;
        #pragma unroll
        for (int ks = 0; ks < 4; ks++) acc = MFMA(am[ks], FRAG(Psl, gct, ks, lane), acc);
        #pragma unroll
        for (int ks = 0; ks < 4; ks++) acc = MFMA(ar[ks], FRAG(Psr, gct, ks, lane), acc);
        float bb = bsl[gct * 16 + m];
        #pragma unroll
        for (int reg = 0; reg < 4; reg++)
            h2[(size_t)(rt * 16 + quad * 4 + reg) * 128 + gct * 16 + m] =
                f2b(fmaxf(acc[reg] + bb, 0.f));
    }
}

// ---------------- fused policy MLP + value head ----------------
// Per wave: 16 rows through gelu(W1), gelu(W2), W3->means; value = h2@Wv+bv.
// LDS C->A transpose per layer, wave-private (no barriers).

__global__ __launch_bounds__(256) void mlp_kernel(
    const unsigned short* __restrict__ h2,
    const unsigned short* __restrict__ P1, const float* __restrict__ b1,
    const unsigned short* __restrict__ P2, const float* __restrict__ b2,
    const unsigned short* __restrict__ P3, const float* __restrict__ b3,
    const float* __restrict__ Wv, const float* __restrict__ bv,
    float* __restrict__ means, float* __restrict__ values, int M)
{
    __shared__ unsigned short z[4][16 * 136];  // stride 136 avoids bank conflicts
    int widx = threadIdx.x >> 6, lane = threadIdx.x & 63;
    int w = blockIdx.x * 4 + widx;
    if (w >= M / 16) return;
    int m = lane & 15, quad = lane >> 4;
    unsigned short* zt = &z[widx][0];
    int r0 = w * 16;

    short8 a[4];
    #pragma unroll
    for (int ks = 0; ks < 4; ks++)
        a[ks] = *(const short8*)(h2 + (size_t)(r0 + m) * 128 + ks * 32 + quad * 8);

    // value head: dot(h2 row, Wv) via quad-split partials
    float p = 0.f;
    #pragma unroll
    for (int ks = 0; ks < 4; ks++) {
        const float* wvp = Wv + ks * 32 + quad * 8;
        float4 w0 = *(const float4*)wvp;
        float4 w1 = *(const float4*)(wvp + 4);
        p = fmaf(b2f((unsigned short)a[ks][0]), w0.x, p);
        p = fmaf(b2f((unsigned short)a[ks][1]), w0.y, p);
        p = fmaf(b2f((unsigned short)a[ks][2]), w0.z, p);
        p = fmaf(b2f((unsigned short)a[ks][3]), w0.w, p);
        p = fmaf(b2f((unsigned short)a[ks][4]), w1.x, p);
        p = fmaf(b2f((unsigned short)a[ks][5]), w1.y, p);
        p = fmaf(b2f((unsigned short)a[ks][6]), w1.z, p);
        p = fmaf(b2f((unsigned short)a[ks][7]), w1.w, p);
    }
    p += __shfl_xor(p, 16);
    p += __shfl_xor(p, 32);
    if (lane < 16) values[r0 + m] = p + bv[0];

    // layer 1: gelu(h2 @ W1 + b1) -> LDS
    #pragma unroll
    for (int ct = 0; ct < 8; ct++) {
        floatx4 acc = {0.f, 0.f, 0.f, 0.f};
        #pragma unroll
        for (int ks = 0; ks < 4; ks++) acc = MFMA(a[ks], FRAG(P1, ct, ks, lane), acc);
        float bb = b1[ct * 16 + m];
        #pragma unroll
        for (int reg = 0; reg < 4; reg++)
            zt[(quad * 4 + reg) * 136 + ct * 16 + m] = f2b(gelu_exact(acc[reg] + bb));
    }
    short8 a2[4];
    #pragma unroll
    for (int ks = 0; ks < 4; ks++)
        a2[ks] = *(const short8*)(zt + m * 136 + ks * 32 + quad * 8);

    // layer 2: gelu(z1 @ W2 + b2) -> LDS
    #pragma unroll
    for (int ct = 0; ct < 8; ct++) {
        floatx4 acc = {0.f, 0.f, 0.f, 0.f};
        #pragma unroll
        for (int ks = 0; ks < 4; ks++) acc = MFMA(a2[ks], FRAG(P2, ct, ks, lane), acc);
        float bb = b2[ct * 16 + m];
        #pragma unroll
        for (int reg = 0; reg < 4; reg++)
            zt[(quad * 4 + reg) * 136 + ct * 16 + m] = f2b(gelu_exact(acc[reg] + bb));
    }
    short8 a3[4];
    #pragma unroll
    for (int ks = 0; ks < 4; ks++)
        a3[ks] = *(const short8*)(zt + m * 136 + ks * 32 + quad * 8);

    // layer 3: means = z2 @ W3 + b3  (NCOL=64)
    #pragma unroll
    for (int ct = 0; ct < 4; ct++) {
        floatx4 acc = {0.f, 0.f, 0.f, 0.f};
        #pragma unroll
        for (int ks = 0; ks < 4; ks++) acc = MFMA(a3[ks], FRAG(P3, ct, ks, lane), acc);
        float bb = b3[ct * 16 + m];
        #pragma unroll
        for (int reg = 0; reg < 4; reg++)
            means[(size_t)(r0 + quad * 4 + reg) * 64 + ct * 16 + m] = acc[reg] + bb;
    }
}

// ---------------- launch ----------------

extern "C" void kernel_launch(void* const* d_in, const int* in_sizes, int n_in,
                              void* d_out, int out_size, void* d_ws, size_t ws_size,
                              hipStream_t stream) {
    const float* feat  = (const float*)d_in[0];
    const int*   eidx  = (const int*)d_in[1];
    const float* W_gcn = (const float*)d_in[2];
    // d_in[3] = b_gcn
    const float* b_gcn = (const float*)d_in[3];
    const float* W_sl  = (const float*)d_in[4];
    const float* b_sl  = (const float*)d_in[5];
    const float* W_sr  = (const float*)d_in[6];
    const float* W1    = (const float*)d_in[7];
    const float* b1    = (const float*)d_in[8];
    const float* W2    = (const float*)d_in[9];
    const float* b2    = (const float*)d_in[10];
    const float* W3    = (const float*)d_in[11];
    const float* b3    = (const float*)d_in[12];
    const float* Wv    = (const float*)d_in[13];
    const float* bv    = (const float*)d_in[14];

    const int N = in_sizes[0] / 128;
    const int E = in_sizes[1] / 2;

    char* ws = (char*)d_ws;
    size_t off = 0;
    auto alloc = [&](size_t bytes) -> void* {
        void* p = ws + off;
        off += (bytes + 255) & ~(size_t)255;
        return p;
    };
    int*   cnt     = (int*)alloc((size_t)N * 4);
    int*   rank    = (int*)alloc((size_t)E * 4);
    int*   row_ptr = (int*)alloc((size_t)(N + 1) * 4);
    int*   bsums   = (int*)alloc(32 * 4);
    float* dinv    = (float*)alloc((size_t)N * 4);
    float* rcnt    = (float*)alloc((size_t)N * 4);
    int*   col     = (int*)alloc((size_t)E * 4);
    unsigned short* xs   = (unsigned short*)alloc((size_t)N * 128 * 2);
    unsigned short* h1   = (unsigned short*)alloc((size_t)N * 128 * 2);
    unsigned short* mean = (unsigned short*)alloc((size_t)N * 128 * 2);
    unsigned short* h2   = (unsigned short*)alloc((size_t)N * 128 * 2);
    unsigned short* Pg   = (unsigned short*)alloc(2048 * 8 * 2);
    unsigned short* Psl  = (unsigned short*)alloc(2048 * 8 * 2);
    unsigned short* Psr  = (unsigned short*)alloc(2048 * 8 * 2);
    unsigned short* P1   = (unsigned short*)alloc(2048 * 8 * 2);
    unsigned short* P2   = (unsigned short*)alloc(2048 * 8 * 2);
    unsigned short* P3   = (unsigned short*)alloc(1024 * 8 * 2);

    hipMemsetAsync(cnt, 0, (size_t)N * 4, stream);

    const int countBlocks = (E + 255) / 256;          // 2500
    const int packBlocks  = (11264 + 255) / 256;      // 44
    count_pack_kernel<<<countBlocks + packBlocks, 256, 0, stream>>>(
        eidx, E, cnt, rank, W_gcn, W_sl, W_sr, W1, W2, W3,
        Pg, Psl, Psr, P1, P2, P3, countBlocks);

    const int NB = (N + 1023) / 1024;                 // 20
    const int gcnBlocks = ((N / 16) * 2 + 3) / 4;     // 625
    scanA_gemm_kernel<<<NB + gcnBlocks, 256, 0, stream>>>(
        cnt, N, row_ptr, bsums, NB, feat, Pg, xs, N);

    scanC_kernel<<<NB, 256, 0, stream>>>(cnt, bsums, N, E, row_ptr, dinv, rcnt);

    fill_kernel<<<(E + 255) / 256, 256, 0, stream>>>(eidx, rank, row_ptr, E, col);

    const int agrid = (N + 3) / 4;
    agg_kernel<true><<<agrid, 256, 0, stream>>>(xs, row_ptr, col, dinv, rcnt, b_gcn, h1, N);
    agg_kernel<false><<<agrid, 256, 0, stream>>>(h1, row_ptr, col, dinv, rcnt, nullptr, mean, N);

    sage_gemm_kernel<<<gcnBlocks, 256, 0, stream>>>(mean, h1, Psl, Psr, b_sl, h2, N);

    mlp_kernel<<<(N / 16 + 3) / 4, 256, 0, stream>>>(
        h2, P1, b1, P2, b2, P3, b3, Wv, bv,
        (float*)d_out, (float*)d_out + (size_t)N * 64, N);
}

// Round 3
// 200.453 us; speedup vs baseline: 1.8395x; 1.0231x over previous
//
#include <hip/hip_runtime.h>
#include <math.h>

// N = 20000, E = 640000, IN_DIM = HID = 128, OUT = 64
// Activations bf16 (ushort bits), accumulation fp32 via MFMA 16x16x32.

typedef __attribute__((ext_vector_type(8))) short short8;
typedef __attribute__((ext_vector_type(4))) float floatx4;

__device__ __forceinline__ unsigned short f2b(float f) {
    unsigned u = __float_as_uint(f);
    unsigned r = (u + 0x7fffu + ((u >> 16) & 1u)) >> 16;
    return (unsigned short)r;
}
__device__ __forceinline__ float b2f(unsigned short h) {
    return __uint_as_float(((unsigned)h) << 16);
}
__device__ __forceinline__ float b2f_lo(unsigned v) {
    return __uint_as_float(v << 16);
}
__device__ __forceinline__ float b2f_hi(unsigned v) {
    return __uint_as_float(v & 0xffff0000u);
}
__device__ __forceinline__ floatx4 MFMA(short8 a, short8 b, floatx4 c) {
    return __builtin_amdgcn_mfma_f32_16x16x32_bf16(a, b, c, 0, 0, 0);
}
__device__ __forceinline__ float gelu_exact(float x) {
    return 0.5f * x * (1.0f + erff(x * 0.70710678118654752440f));
}

// B fragment for (ct, ks) at lane: packed W layout
#define FRAG(P, ct, ks, lane) (*(const short8*)((P) + (((((ct)*4 + (ks))*64) + (lane)) << 3)))

// ---------------- count (+rank) fused with weight packing ----------------

__global__ __launch_bounds__(256) void count_pack_kernel(
    const int* __restrict__ eidx, int E,
    int* __restrict__ cnt, int* __restrict__ rank,
    const float* Wg, const float* Wsl, const float* Wsr,
    const float* W1, const float* W2, const float* W3,
    unsigned short* Pg, unsigned short* Psl, unsigned short* Psr,
    unsigned short* P1, unsigned short* P2, unsigned short* P3,
    int countBlocks)
{
    if ((int)blockIdx.x < countBlocks) {
        int e = blockIdx.x * 256 + threadIdx.x;
        if (e < E) {
            int d = eidx[E + e];
            rank[e] = atomicAdd(&cnt[d], 1);
        }
        return;
    }
    int t = (blockIdx.x - countBlocks) * 256 + threadIdx.x;
    const float* W; unsigned short* P; int NC = 128; int base;
    if (t < 2048)       { W = Wg;  P = Pg;  base = t; }
    else if (t < 4096)  { W = Wsl; P = Psl; base = t - 2048; }
    else if (t < 6144)  { W = Wsr; P = Psr; base = t - 4096; }
    else if (t < 8192)  { W = W1;  P = P1;  base = t - 6144; }
    else if (t < 10240) { W = W2;  P = P2;  base = t - 8192; }
    else if (t < 11264) { W = W3;  P = P3;  base = t - 10240; NC = 64; }
    else return;
    int l  = base & 63;
    int ks = (base >> 6) & 3;
    int ct = base >> 8;
    int n  = ct * 16 + (l & 15);
    int k0 = ks * 32 + ((l >> 4) << 3);
    short8 v;
    #pragma unroll
    for (int j = 0; j < 8; j++) v[j] = (short)f2b(W[(size_t)(k0 + j) * NC + n]);
    *(short8*)(P + ((size_t)base << 3)) = v;
}

// ---------------- scan (per-block local prefix + block sums + dinv) ---------

__global__ __launch_bounds__(256) void scan_kernel(
    const int* __restrict__ cnt, int N,
    int* __restrict__ row_ptr, int* __restrict__ bsums,
    float* __restrict__ dinv)
{
    __shared__ int sh[256];
    int b = blockIdx.x, tid = threadIdx.x;
    int i0 = b * 1024 + tid * 4;
    int v0 = (i0 + 0 < N) ? cnt[i0 + 0] : 0;
    int v1 = (i0 + 1 < N) ? cnt[i0 + 1] : 0;
    int v2 = (i0 + 2 < N) ? cnt[i0 + 2] : 0;
    int v3 = (i0 + 3 < N) ? cnt[i0 + 3] : 0;
    int tot = v0 + v1 + v2 + v3;
    sh[tid] = tot;
    __syncthreads();
    for (int off = 1; off < 256; off <<= 1) {
        int t = (tid >= off) ? sh[tid - off] : 0;
        __syncthreads();
        sh[tid] += t;
        __syncthreads();
    }
    int excl = sh[tid] - tot;
    if (i0 + 0 < N) { row_ptr[i0 + 0] = excl;                dinv[i0 + 0] = rsqrtf((float)(v0 + 1)); }
    if (i0 + 1 < N) { row_ptr[i0 + 1] = excl + v0;           dinv[i0 + 1] = rsqrtf((float)(v1 + 1)); }
    if (i0 + 2 < N) { row_ptr[i0 + 2] = excl + v0 + v1;      dinv[i0 + 2] = rsqrtf((float)(v2 + 1)); }
    if (i0 + 3 < N) { row_ptr[i0 + 3] = excl + v0 + v1 + v2; dinv[i0 + 3] = rsqrtf((float)(v3 + 1)); }
    if (tid == 255) bsums[b] = sh[255];
}

// ---------------- fill (atomic-free scatter) + GCN GEMM in one dispatch -----

__global__ __launch_bounds__(256) void fill_gemm_kernel(
    const int* __restrict__ eidx, const int* __restrict__ rank,
    const int* __restrict__ row_ptr, const int* __restrict__ bsums,
    int E, int* __restrict__ col,
    const float* __restrict__ feat, const unsigned short* __restrict__ Pg,
    unsigned short* __restrict__ xs, int M, int fillBlocks)
{
    if ((int)blockIdx.x < fillBlocks) {
        int e = blockIdx.x * 256 + threadIdx.x;
        if (e < E) {
            int d = eidx[E + e];
            int b = d >> 10;
            int off = 0;
            for (int j = 0; j < b; j++) off += bsums[j];
            col[off + row_ptr[d] + rank[e]] = eidx[e];
        }
        return;
    }
    // GCN GEMM: wave computes 16 rows x 64 cols of xs = bf16(feat @ Wg)
    int bid = blockIdx.x - fillBlocks;
    int w = bid * 4 + (threadIdx.x >> 6);
    if (w >= (M / 16) * 2) return;
    int lane = threadIdx.x & 63;
    int m = lane & 15, quad = lane >> 4;
    int rt = w >> 1, ch = w & 1;
    const float* arow = feat + (size_t)(rt * 16 + m) * 128;
    short8 a[4];
    #pragma unroll
    for (int ks = 0; ks < 4; ks++) {
        float4 f0 = *(const float4*)(arow + ks * 32 + quad * 8);
        float4 f1 = *(const float4*)(arow + ks * 32 + quad * 8 + 4);
        short8 s;
        s[0] = (short)f2b(f0.x); s[1] = (short)f2b(f0.y);
        s[2] = (short)f2b(f0.z); s[3] = (short)f2b(f0.w);
        s[4] = (short)f2b(f1.x); s[5] = (short)f2b(f1.y);
        s[6] = (short)f2b(f1.z); s[7] = (short)f2b(f1.w);
        a[ks] = s;
    }
    #pragma unroll
    for (int ct = 0; ct < 4; ct++) {
        floatx4 acc = {0.f, 0.f, 0.f, 0.f};
        #pragma unroll
        for (int ks = 0; ks < 4; ks++)
            acc = MFMA(a[ks], FRAG(Pg, ch * 4 + ct, ks, lane), acc);
        #pragma unroll
        for (int reg = 0; reg < 4; reg++)
            xs[(size_t)(rt * 16 + quad * 4 + reg) * 128 + (ch * 4 + ct) * 16 + m] =
                f2b(acc[reg]);
    }
}

// ---------------- aggregation: 16 lanes per edge-row, uint4 gathers ---------
// GCN:  h1[d] = relu(dinv[d]*(sum_s dinv[s]*xs[s] + dinv[d]*xs[d]) + b)
// SAGE: mean[d] = (1/max(deg,1)) * sum_s h1[s]

template<bool GCN>
__global__ __launch_bounds__(256) void agg_kernel(
    const unsigned short* __restrict__ X, const int* __restrict__ row_ptr,
    const int* __restrict__ bsums, const int* __restrict__ col,
    const float* __restrict__ dinv, const float* __restrict__ bias,
    unsigned short* __restrict__ Y, int N, int E)
{
    int w = (int)((blockIdx.x * 256 + threadIdx.x) >> 6);
    if (w >= N) return;
    int lane = threadIdx.x & 63;
    int g = lane >> 4, t = lane & 15;
    const uint4* Xq = (const uint4*)X;

    // absolute edge range from local prefix + block sums
    int b = w >> 10;
    int off = 0;
    for (int j = 0; j < b; j++) off += bsums[j];
    int beg = off + row_ptr[w];
    int end;
    if (w + 1 < N) {
        int off2 = (((w + 1) >> 10) != b) ? off + bsums[b] : off;
        end = off2 + row_ptr[w + 1];
    } else end = E;
    int deg = end - beg;

    float acc[8] = {0.f, 0.f, 0.f, 0.f, 0.f, 0.f, 0.f, 0.f};

    for (int base = beg; base < end; base += 64) {
        int rem = end - base;
        int n = rem < 64 ? rem : 64;
        int idx = (lane < n) ? col[base + lane] : 0;
        for (int j0 = 0; j0 < n; j0 += 16) {
            #pragma unroll
            for (int u = 0; u < 4; u++) {
                int j = j0 + u * 4 + g;
                int s = __shfl(idx, j & 63);
                if (j < n) {
                    uint4 q = Xq[(size_t)s * 16 + t];
                    float sc = GCN ? dinv[s] : 1.0f;
                    acc[0] = fmaf(b2f_lo(q.x), sc, acc[0]);
                    acc[1] = fmaf(b2f_hi(q.x), sc, acc[1]);
                    acc[2] = fmaf(b2f_lo(q.y), sc, acc[2]);
                    acc[3] = fmaf(b2f_hi(q.y), sc, acc[3]);
                    acc[4] = fmaf(b2f_lo(q.z), sc, acc[4]);
                    acc[5] = fmaf(b2f_hi(q.z), sc, acc[5]);
                    acc[6] = fmaf(b2f_lo(q.w), sc, acc[6]);
                    acc[7] = fmaf(b2f_hi(q.w), sc, acc[7]);
                }
            }
        }
    }
    // reduce across the 4 groups
    #pragma unroll
    for (int i = 0; i < 8; i++) {
        acc[i] += __shfl_xor(acc[i], 16);
        acc[i] += __shfl_xor(acc[i], 32);
    }
    if (g == 0) {
        float out[8];
        if (GCN) {
            float dw = dinv[w];
            uint4 q = Xq[(size_t)w * 16 + t];  // self loop
            acc[0] = fmaf(b2f_lo(q.x), dw, acc[0]);
            acc[1] = fmaf(b2f_hi(q.x), dw, acc[1]);
            acc[2] = fmaf(b2f_lo(q.y), dw, acc[2]);
            acc[3] = fmaf(b2f_hi(q.y), dw, acc[3]);
            acc[4] = fmaf(b2f_lo(q.z), dw, acc[4]);
            acc[5] = fmaf(b2f_hi(q.z), dw, acc[5]);
            acc[6] = fmaf(b2f_lo(q.w), dw, acc[6]);
            acc[7] = fmaf(b2f_hi(q.w), dw, acc[7]);
            float4 b0 = *(const float4*)(bias + t * 8);
            float4 b1 = *(const float4*)(bias + t * 8 + 4);
            out[0] = fmaxf(fmaf(acc[0], dw, b0.x), 0.f);
            out[1] = fmaxf(fmaf(acc[1], dw, b0.y), 0.f);
            out[2] = fmaxf(fmaf(acc[2], dw, b0.z), 0.f);
            out[3] = fmaxf(fmaf(acc[3], dw, b0.w), 0.f);
            out[4] = fmaxf(fmaf(acc[4], dw, b1.x), 0.f);
            out[5] = fmaxf(fmaf(acc[5], dw, b1.y), 0.f);
            out[6] = fmaxf(fmaf(acc[6], dw, b1.z), 0.f);
            out[7] = fmaxf(fmaf(acc[7], dw, b1.w), 0.f);
        } else {
            float rc = 1.0f / (float)(deg > 0 ? deg : 1);
            #pragma unroll
            for (int i = 0; i < 8; i++) out[i] = acc[i] * rc;
        }
        uint4 r;
        r.x = (unsigned)f2b(out[0]) | ((unsigned)f2b(out[1]) << 16);
        r.y = (unsigned)f2b(out[2]) | ((unsigned)f2b(out[3]) << 16);
        r.z = (unsigned)f2b(out[4]) | ((unsigned)f2b(out[5]) << 16);
        r.w = (unsigned)f2b(out[6]) | ((unsigned)f2b(out[7]) << 16);
        ((uint4*)Y)[(size_t)w * 16 + t] = r;
    }
}

// ---------------- fused SAGE + policy MLP + value head ----------------
// Per wave: 16 rows. h2 = relu(mean@Wsl + h1@Wsr + bsl) stays in LDS;
// then gelu(W1), gelu(W2), W3 -> means; value = h2@Wv+bv from C-layout.

__global__ __launch_bounds__(256) void sage_mlp_kernel(
    const unsigned short* __restrict__ mean, const unsigned short* __restrict__ h1,
    const unsigned short* __restrict__ Psl, const unsigned short* __restrict__ Psr,
    const float* __restrict__ bsl,
    const unsigned short* __restrict__ P1, const float* __restrict__ b1,
    const unsigned short* __restrict__ P2, const float* __restrict__ b2,
    const unsigned short* __restrict__ P3, const float* __restrict__ b3,
    const float* __restrict__ Wv, const float* __restrict__ bv,
    float* __restrict__ means, float* __restrict__ values, int M)
{
    __shared__ unsigned short z[4][16 * 136];
    int widx = threadIdx.x >> 6, lane = threadIdx.x & 63;
    int w = blockIdx.x * 4 + widx;
    if (w >= M / 16) return;
    int m = lane & 15, quad = lane >> 4;
    unsigned short* zt = &z[widx][0];
    int r0 = w * 16;

    short8 am[4], ar[4];
    #pragma unroll
    for (int ks = 0; ks < 4; ks++) {
        am[ks] = *(const short8*)(mean + (size_t)(r0 + m) * 128 + ks * 32 + quad * 8);
        ar[ks] = *(const short8*)(h1   + (size_t)(r0 + m) * 128 + ks * 32 + quad * 8);
    }

    // SAGE layer: h2 -> LDS (bf16) + value-head partials from C-layout
    float vpart[4] = {0.f, 0.f, 0.f, 0.f};
    #pragma unroll
    for (int ct = 0; ct < 8; ct++) {
        floatx4 acc = {0.f, 0.f, 0.f, 0.f};
        #pragma unroll
        for (int ks = 0; ks < 4; ks++) acc = MFMA(am[ks], FRAG(Psl, ct, ks, lane), acc);
        #pragma unroll
        for (int ks = 0; ks < 4; ks++) acc = MFMA(ar[ks], FRAG(Psr, ct, ks, lane), acc);
        float bb = bsl[ct * 16 + m];
        float wv = Wv[ct * 16 + m];
        #pragma unroll
        for (int reg = 0; reg < 4; reg++) {
            float o = fmaxf(acc[reg] + bb, 0.f);
            vpart[reg] = fmaf(o, wv, vpart[reg]);
            zt[(quad * 4 + reg) * 136 + ct * 16 + m] = f2b(o);
        }
    }
    // value: reduce across m-lanes within each quad
    #pragma unroll
    for (int off = 1; off <= 8; off <<= 1) {
        #pragma unroll
        for (int reg = 0; reg < 4; reg++)
            vpart[reg] += __shfl_xor(vpart[reg], off);
    }
    if (m == 0) {
        float bvv = bv[0];
        #pragma unroll
        for (int reg = 0; reg < 4; reg++)
            values[r0 + quad * 4 + reg] = vpart[reg] + bvv;
    }

    short8 a1[4];
    #pragma unroll
    for (int ks = 0; ks < 4; ks++)
        a1[ks] = *(const short8*)(zt + m * 136 + ks * 32 + quad * 8);

    // layer 1: gelu(h2 @ W1 + b1) -> LDS
    #pragma unroll
    for (int ct = 0; ct < 8; ct++) {
        floatx4 acc = {0.f, 0.f, 0.f, 0.f};
        #pragma unroll
        for (int ks = 0; ks < 4; ks++) acc = MFMA(a1[ks], FRAG(P1, ct, ks, lane), acc);
        float bb = b1[ct * 16 + m];
        #pragma unroll
        for (int reg = 0; reg < 4; reg++)
            zt[(quad * 4 + reg) * 136 + ct * 16 + m] = f2b(gelu_exact(acc[reg] + bb));
    }
    short8 a2[4];
    #pragma unroll
    for (int ks = 0; ks < 4; ks++)
        a2[ks] = *(const short8*)(zt + m * 136 + ks * 32 + quad * 8);

    // layer 2: gelu(z1 @ W2 + b2) -> LDS
    #pragma unroll
    for (int ct = 0; ct < 8; ct++) {
        floatx4 acc = {0.f, 0.f, 0.f, 0.f};
        #pragma unroll
        for (int ks = 0; ks < 4; ks++) acc = MFMA(a2[ks], FRAG(P2, ct, ks, lane), acc);
        float bb = b2[ct * 16 + m];
        #pragma unroll
        for (int reg = 0; reg < 4; reg++)
            zt[(quad * 4 + reg) * 136 + ct * 16 + m] = f2b(gelu_exact(acc[reg] + bb));
    }
    short8 a3[4];
    #pragma unroll
    for (int ks = 0; ks < 4; ks++)
        a3[ks] = *(const short8*)(zt + m * 136 + ks * 32 + quad * 8);

    // layer 3: means = z2 @ W3 + b3  (64 cols)
    #pragma unroll
    for (int ct = 0; ct < 4; ct++) {
        floatx4 acc = {0.f, 0.f, 0.f, 0.f};
        #pragma unroll
        for (int ks = 0; ks < 4; ks++) acc = MFMA(a3[ks], FRAG(P3, ct, ks, lane), acc);
        float bb = b3[ct * 16 + m];
        #pragma unroll
        for (int reg = 0; reg < 4; reg++)
            means[(size_t)(r0 + quad * 4 + reg) * 64 + ct * 16 + m] = acc[reg] + bb;
    }
}

// ---------------- launch ----------------

extern "C" void kernel_launch(void* const* d_in, const int* in_sizes, int n_in,
                              void* d_out, int out_size, void* d_ws, size_t ws_size,
                              hipStream_t stream) {
    const float* feat  = (const float*)d_in[0];
    const int*   eidx  = (const int*)d_in[1];
    const float* W_gcn = (const float*)d_in[2];
    const float* b_gcn = (const float*)d_in[3];
    const float* W_sl  = (const float*)d_in[4];
    const float* b_sl  = (const float*)d_in[5];
    const float* W_sr  = (const float*)d_in[6];
    const float* W1    = (const float*)d_in[7];
    const float* b1    = (const float*)d_in[8];
    const float* W2    = (const float*)d_in[9];
    const float* b2    = (const float*)d_in[10];
    const float* W3    = (const float*)d_in[11];
    const float* b3    = (const float*)d_in[12];
    const float* Wv    = (const float*)d_in[13];
    const float* bv    = (const float*)d_in[14];

    const int N = in_sizes[0] / 128;
    const int E = in_sizes[1] / 2;

    char* ws = (char*)d_ws;
    size_t off = 0;
    auto alloc = [&](size_t bytes) -> void* {
        void* p = ws + off;
        off += (bytes + 255) & ~(size_t)255;
        return p;
    };
    int*   cnt     = (int*)alloc((size_t)N * 4);
    int*   rank    = (int*)alloc((size_t)E * 4);
    int*   row_ptr = (int*)alloc((size_t)N * 4);
    int*   bsums   = (int*)alloc(32 * 4);
    float* dinv    = (float*)alloc((size_t)N * 4);
    int*   col     = (int*)alloc((size_t)E * 4);
    unsigned short* xs   = (unsigned short*)alloc((size_t)N * 128 * 2);
    unsigned short* h1   = (unsigned short*)alloc((size_t)N * 128 * 2);
    unsigned short* mean = (unsigned short*)alloc((size_t)N * 128 * 2);
    unsigned short* Pg   = (unsigned short*)alloc(2048 * 8 * 2);
    unsigned short* Psl  = (unsigned short*)alloc(2048 * 8 * 2);
    unsigned short* Psr  = (unsigned short*)alloc(2048 * 8 * 2);
    unsigned short* P1   = (unsigned short*)alloc(2048 * 8 * 2);
    unsigned short* P2   = (unsigned short*)alloc(2048 * 8 * 2);
    unsigned short* P3   = (unsigned short*)alloc(1024 * 8 * 2);

    hipMemsetAsync(cnt, 0, (size_t)N * 4, stream);

    const int countBlocks = (E + 255) / 256;          // 2500
    const int packBlocks  = (11264 + 255) / 256;      // 44
    count_pack_kernel<<<countBlocks + packBlocks, 256, 0, stream>>>(
        eidx, E, cnt, rank, W_gcn, W_sl, W_sr, W1, W2, W3,
        Pg, Psl, Psr, P1, P2, P3, countBlocks);

    const int NB = (N + 1023) / 1024;                 // 20
    scan_kernel<<<NB, 256, 0, stream>>>(cnt, N, row_ptr, bsums, dinv);

    const int fillBlocks = (E + 255) / 256;           // 2500
    const int gemmBlocks = ((N / 16) * 2 + 3) / 4;    // 625
    fill_gemm_kernel<<<fillBlocks + gemmBlocks, 256, 0, stream>>>(
        eidx, rank, row_ptr, bsums, E, col, feat, Pg, xs, N, fillBlocks);

    const int agrid = (N + 3) / 4;
    agg_kernel<true><<<agrid, 256, 0, stream>>>(xs, row_ptr, bsums, col, dinv, b_gcn, h1, N, E);
    agg_kernel<false><<<agrid, 256, 0, stream>>>(h1, row_ptr, bsums, col, dinv, nullptr, mean, N, E);

    sage_mlp_kernel<<<(N / 16 + 3) / 4, 256, 0, stream>>>(
        mean, h1, Psl, Psr, b_sl, P1, b1, P2, b2, P3, b3, Wv, bv,
        (float*)d_out, (float*)d_out + (size_t)N * 64, N);
}